// Round 2
// baseline (289.156 us; speedup 1.0000x reference)
//
#include <hip/hip_runtime.h>

#define KN 12
#define DNBR 320
#define DNEW 256
#define BN_TOT 8192
#define ATB 2                 // atoms per block
#define NKS_E 10              // 320/32
#define NKS_H 8               // 256/32
#define ASTR_H 264            // A_h row stride in u16 (256 + 8 pad)
#define H_OFF 294912          // byte offset of precomputed h in workspace (after B2)

typedef short bf8_t __attribute__((ext_vector_type(8)));
typedef float f32x4 __attribute__((ext_vector_type(4)));
typedef unsigned short us8 __attribute__((ext_vector_type(8)));
using u16 = unsigned short;
using u32 = unsigned int;

__device__ __forceinline__ u16 f2bf(float f) {
    u32 x = __float_as_uint(f);
    return (u16)((x + 0x7fffu + ((x >> 16) & 1u)) >> 16);  // RNE
}

__device__ __forceinline__ us8 pack8(float4 a, float4 b) {
    us8 v;
    v[0] = f2bf(a.x); v[1] = f2bf(a.y); v[2] = f2bf(a.z); v[3] = f2bf(a.w);
    v[4] = f2bf(b.x); v[5] = f2bf(b.y); v[6] = f2bf(b.z); v[7] = f2bf(b.w);
    return v;
}

// 8 fp32 -> 8 bf16 via HW packed convert (RNE, bit-identical to f2bf)
__device__ __forceinline__ bf8_t cvt8(float4 a, float4 b) {
    u32 r0, r1, r2, r3;
    asm("v_cvt_pk_bf16_f32 %0, %1, %2" : "=v"(r0) : "v"(a.x), "v"(a.y));
    asm("v_cvt_pk_bf16_f32 %0, %1, %2" : "=v"(r1) : "v"(a.z), "v"(a.w));
    asm("v_cvt_pk_bf16_f32 %0, %1, %2" : "=v"(r2) : "v"(b.x), "v"(b.y));
    asm("v_cvt_pk_bf16_f32 %0, %1, %2" : "=v"(r3) : "v"(b.z), "v"(b.w));
    union { u32 u[4]; bf8_t v; } cv;
    cv.u[0] = r0; cv.u[1] = r1; cv.u[2] = r2; cv.u[3] = r3;
    return cv.v;
}

// ---- kernel 1: fragment-major stacked B2: tiles 0..159 = Wn (10 ks x 16 nt),
// tiles 160..287 = Wa (8 ks x 16 nt). Tile = 64 lanes x 8 u16 (1KB). ----
__global__ __launch_bounds__(256) void build_b2(
    const float* __restrict__ Wn, const float* __restrict__ Wa,
    u16* __restrict__ B2)
{
    int tile = blockIdx.x * 4 + (threadIdx.x >> 6);   // 0..287
    int l = threadIdx.x & 63;
    int q = l >> 4, m = l & 15;
    us8 v;
    if (tile < 160) {
        int ks = tile >> 4, nt = tile & 15;
        int col = nt * 16 + m;
#pragma unroll
        for (int e = 0; e < 8; e++)
            v[e] = f2bf(Wn[(ks * 32 + q * 8 + e) * DNEW + col]);
    } else {
        int tt = tile - 160;
        int ks = tt >> 4, nt = tt & 15;
        int col = nt * 16 + m;
#pragma unroll
        for (int e = 0; e < 8; e++)
            v[e] = f2bf(Wa[(ks * 32 + q * 8 + e) * DNEW + col]);
    }
    *(us8*)&B2[(size_t)tile * 512 + l * 8] = v;
}

// ---- kernel 2: precompute h = atomf @ Wa + ba, fp32 to workspace. 32 atoms/block. ----
__global__ __launch_bounds__(256) void h_pre(
    const float* __restrict__ atomf, const u16* __restrict__ B2,
    const float* __restrict__ ba, float* __restrict__ h_g)
{
    __shared__ u16 A[32 * ASTR_H];   // 16896 B

    const int t = threadIdx.x;
    const int l = t & 63, w = t >> 6, q = l >> 4, m = l & 15;
    const int ab = blockIdx.x * 32;

    // stage 32 atoms x 256 f32 -> bf16 (1024 us8 chunks)
    const float* base = atomf + (size_t)ab * DNEW;
    for (int i = t; i < 1024; i += 256) {
        float4 v0 = *(const float4*)(base + i * 8);
        float4 v1 = *(const float4*)(base + i * 8 + 4);
        int a = i >> 5, c8 = i & 31;
        *(us8*)&A[a * ASTR_H + c8 * 8] = pack8(v0, v1);
    }
    __syncthreads();

    f32x4 acc[2][4];
#pragma unroll
    for (int mt = 0; mt < 2; mt++)
#pragma unroll
        for (int j = 0; j < 4; j++) acc[mt][j] = (f32x4){0.f, 0.f, 0.f, 0.f};

    for (int ks = 0; ks < NKS_H; ks++) {
        bf8_t af0 = *(bf8_t*)&A[m * ASTR_H + ks * 32 + q * 8];
        bf8_t af1 = *(bf8_t*)&A[(16 + m) * ASTR_H + ks * 32 + q * 8];
#pragma unroll
        for (int j = 0; j < 4; j++) {
            bf8_t bfj = *(const bf8_t*)&B2[((size_t)(160 + ks * 16 + w * 4 + j) * 64 + l) * 8];
            acc[0][j] = __builtin_amdgcn_mfma_f32_16x16x32_bf16(af0, bfj, acc[0][j], 0, 0, 0);
            acc[1][j] = __builtin_amdgcn_mfma_f32_16x16x32_bf16(af1, bfj, acc[1][j], 0, 0, 0);
        }
    }
#pragma unroll
    for (int mt = 0; mt < 2; mt++)
#pragma unroll
        for (int j = 0; j < 4; j++) {
            int col = w * 64 + j * 16 + m;
            float bav = ba[col];
#pragma unroll
            for (int r = 0; r < 4; r++) {
                int row = ab + mt * 16 + q * 4 + r;
                h_g[(size_t)row * DNEW + col] = acc[mt][j][r] + bav;
            }
        }
}

// ---- kernel 3: fused e-GEMM + GATv2 attention + LN. 2 atoms/block.
// A-fragments loaded DIRECTLY from global fp32 -> cvt_pk bf16 in registers:
// no LDS staging, no pack/reload round-trip, one barrier (LN reduce) total. ----
__global__ __launch_bounds__(256, 4) void fused_all(
    const float* __restrict__ nbrf,
    const float* __restrict__ smaskg, const float* __restrict__ amaskg,
    const u16* __restrict__ B2, const float* __restrict__ h_g,
    const float* __restrict__ bnb, const float* __restrict__ walg,
    const float* __restrict__ balg, const float* __restrict__ gam,
    const float* __restrict__ bet, float* __restrict__ out)
{
    __shared__ float red_l[ATB][8];          // 64 B

    const int t = threadIdx.x;
    const int l = t & 63, w = t >> 6, q = l >> 4, m = l & 15;
    const int a0 = blockIdx.x * ATB;

    // ---- per-lane params (independent loads; issue early) ----
    const float bal = balg[0];
    float hv[ATB][4], bnbv[4], wv[4];
#pragma unroll
    for (int j = 0; j < 4; j++) {
        int col = w * 64 + j * 16 + m;
        hv[0][j] = h_g[(size_t)(a0 + 0) * DNEW + col];
        hv[1][j] = h_g[(size_t)(a0 + 1) * DNEW + col];
        bnbv[j] = bnb[col];
        wv[j] = walg[(j * 16 + m) & 31];
    }
    const bool qv = (q < 3);
    float smv[ATB][4], amv[ATB][4];
#pragma unroll
    for (int at = 0; at < ATB; at++)
#pragma unroll
        for (int r = 0; r < 4; r++) {
            int k = q * 4 + r;
            smv[at][r] = qv ? smaskg[(size_t)(a0 + at) * KN + k] + bal : 0.f;
            amv[at][r] = qv ? amaskg[(size_t)(a0 + at) * KN + k] : 0.f;
        }

    // ---- e-GEMM, A direct from global. lane(q,m): row m (m<12 real, else 0),
    // k-slice q*8. Per wave-load: 12 contiguous 128B row segments. ----
    const bool mval = (m < KN);
    const float* ab0 = nbrf + ((size_t)(a0 + 0) * KN + m) * DNBR;
    const float* ab1 = nbrf + ((size_t)(a0 + 1) * KN + m) * DNBR;
    const int ko = q * 8;

    f32x4 acc_e[ATB][4];
#pragma unroll
    for (int at = 0; at < ATB; at++)
#pragma unroll
        for (int j = 0; j < 4; j++) acc_e[at][j] = (f32x4){0.f, 0.f, 0.f, 0.f};

#pragma unroll
    for (int ks = 0; ks < NKS_E; ks++) {
        bf8_t af0 = (bf8_t){0, 0, 0, 0, 0, 0, 0, 0};
        bf8_t af1 = (bf8_t){0, 0, 0, 0, 0, 0, 0, 0};
        if (mval) {
            const float* p0 = ab0 + ks * 32 + ko;
            const float* p1 = ab1 + ks * 32 + ko;
            af0 = cvt8(*(const float4*)p0, *(const float4*)(p0 + 4));
            af1 = cvt8(*(const float4*)p1, *(const float4*)(p1 + 4));
        }
#pragma unroll
        for (int j = 0; j < 4; j++) {
            bf8_t bfj = *(const bf8_t*)&B2[((size_t)(ks * 16 + w * 4 + j) * 64 + l) * 8];
            acc_e[0][j] = __builtin_amdgcn_mfma_f32_16x16x32_bf16(af0, bfj, acc_e[0][j], 0, 0, 0);
            acc_e[1][j] = __builtin_amdgcn_mfma_f32_16x16x32_bf16(af1, bfj, acc_e[1][j], 0, 0, 0);
        }
    }

    // ---- e_reg = acc_e + bnb (true e) ----
#pragma unroll
    for (int j = 0; j < 4; j++) {
#pragma unroll
        for (int at = 0; at < ATB; at++)
#pragma unroll
            for (int r = 0; r < 4; r++) acc_e[at][j][r] += bnbv[j];
    }

    // ---- scores + softmax + attn + ctx: all wave-local (wave w owns heads 2w,2w+1) ----
    float ctxv[ATB][4];
#pragma unroll
    for (int at = 0; at < ATB; at++) {
        float s1 = 0.f, s2 = 0.f;
#pragma unroll
        for (int jj = 0; jj < 2; jj++) {
            // scores: p[r] for neighbor k = q*4+r (q==3 rows masked out)
            float p[4];
#pragma unroll
            for (int r = 0; r < 4; r++) {
                float pp = 0.f;
#pragma unroll
                for (int jo = 0; jo < 2; jo++) {
                    int j = jj * 2 + jo;
                    float f = acc_e[at][j][r] + hv[at][j];
                    f = f > 0.f ? f : 0.01f * f;
                    pp = fmaf(f, wv[j], pp);
                }
                pp += __shfl_xor(pp, 1);
                pp += __shfl_xor(pp, 2);
                pp += __shfl_xor(pp, 4);
                pp += __shfl_xor(pp, 8);
                p[r] = qv ? pp + smv[at][r] : -1e30f;
            }
            // softmax over 12 neighbors (cross-q via shfl 16/32)
            float mx = fmaxf(fmaxf(p[0], p[1]), fmaxf(p[2], p[3]));
            mx = fmaxf(mx, __shfl_xor(mx, 16));
            mx = fmaxf(mx, __shfl_xor(mx, 32));
            float ex[4], ss = 0.f;
#pragma unroll
            for (int r = 0; r < 4; r++) {
                ex[r] = qv ? __expf(p[r] - mx) : 0.f;
                ss += ex[r];
            }
            ss += __shfl_xor(ss, 16);
            ss += __shfl_xor(ss, 32);
            float inv = 1.f / ss;
            float am[4];
#pragma unroll
            for (int r = 0; r < 4; r++)
                am[r] = qv ? ex[r] * inv * amv[at][r] : 0.f;
            // ctx[col] = sum_k attn_k * e_k  (q-reduce via shfl 16/32)
#pragma unroll
            for (int jo = 0; jo < 2; jo++) {
                int j = jj * 2 + jo;
                float cp = am[0] * acc_e[at][j][0] + am[1] * acc_e[at][j][1] +
                           am[2] * acc_e[at][j][2] + am[3] * acc_e[at][j][3];
                cp += __shfl_xor(cp, 16);
                cp += __shfl_xor(cp, 32);
                ctxv[at][j] = cp;
                s1 += cp;
                s2 += cp * cp;
            }
        }
        // LN partial sums: reduce over m-group -> wave total over its 64 cols
#pragma unroll
        for (int off = 1; off < 16; off <<= 1) {
            s1 += __shfl_xor(s1, off);
            s2 += __shfl_xor(s2, off);
        }
        if (l == 0) { red_l[at][w] = s1; red_l[at][4 + w] = s2; }
    }
    __syncthreads();   // only barrier: LN cross-wave reduce

    // ---- LayerNorm epilogue ----
#pragma unroll
    for (int at = 0; at < ATB; at++) {
        float ts1 = red_l[at][0] + red_l[at][1] + red_l[at][2] + red_l[at][3];
        float ts2 = red_l[at][4] + red_l[at][5] + red_l[at][6] + red_l[at][7];
        float mu = ts1 * (1.f / 256.f);
        float var = ts2 * (1.f / 256.f) - mu * mu;
        var = fmaxf(var, 0.f);
        float rs = rsqrtf(var + 1e-5f);
        if (q == 0) {
#pragma unroll
            for (int j = 0; j < 4; j++) {
                int col = w * 64 + j * 16 + m;
                out[(size_t)(a0 + at) * DNEW + col] =
                    (ctxv[at][j] - mu) * rs * gam[col] + bet[col];
            }
        }
    }
}

extern "C" void kernel_launch(void* const* d_in, const int* in_sizes, int n_in,
                              void* d_out, int out_size, void* d_ws, size_t ws_size,
                              hipStream_t stream) {
    const float* atomf = (const float*)d_in[0];
    const float* nbrf  = (const float*)d_in[1];
    const float* smask = (const float*)d_in[2];
    const float* amask = (const float*)d_in[3];
    const float* Wa    = (const float*)d_in[4];
    const float* ba    = (const float*)d_in[5];
    const float* Wn    = (const float*)d_in[6];
    const float* bnb   = (const float*)d_in[7];
    const float* wal   = (const float*)d_in[8];
    const float* bal   = (const float*)d_in[9];
    const float* gam   = (const float*)d_in[10];
    const float* bet   = (const float*)d_in[11];
    float* outp = (float*)d_out;

    u16* B2 = (u16*)d_ws;                              // 288 KiB
    float* h_g = (float*)((char*)d_ws + H_OFF);        // 8 MiB fp32 h

    build_b2<<<72, 256, 0, stream>>>(Wn, Wa, B2);
    h_pre<<<BN_TOT / 32, 256, 0, stream>>>(atomf, B2, ba, h_g);
    fused_all<<<BN_TOT / ATB, 256, 0, stream>>>(nbrf, smask, amask, B2, h_g,
                                                bnb, wal, bal, gam, bet, outp);
}

// Round 3
// 251.128 us; speedup vs baseline: 1.1514x; 1.1514x over previous
//
#include <hip/hip_runtime.h>

#define KN 12
#define DNBR 320
#define DNEW 256
#define BN_TOT 8192
#define ATB 2                 // atoms per block (fused)
#define HATB 16               // atoms per block (h_pre)
#define NKS_E 10              // 320/32
#define NKS_H 8               // 256/32
#define ASTR_H 264            // h_pre A row stride in u16 (256 + 8 pad)
#define H_OFF 294912          // byte offset of precomputed h in workspace (after B2)
#define NCHUNK 40             // fused A2 chunks: at(2) x ks(10) x half(2), 1KB each

typedef short bf8_t __attribute__((ext_vector_type(8)));
typedef float f32x4 __attribute__((ext_vector_type(4)));
typedef unsigned short us8 __attribute__((ext_vector_type(8)));
using u16 = unsigned short;
using u32 = unsigned int;

typedef __attribute__((address_space(3))) void lds_vp;
typedef __attribute__((address_space(1))) const void gc_vp;

__device__ __forceinline__ void dma16(const void* g, void* l) {
    // async global->LDS: 64 lanes x 16B, LDS dest = base + lane*16
    __builtin_amdgcn_global_load_lds((gc_vp*)g, (lds_vp*)l, 16, 0, 0);
}

__device__ __forceinline__ u16 f2bf(float f) {
    u32 x = __float_as_uint(f);
    return (u16)((x + 0x7fffu + ((x >> 16) & 1u)) >> 16);  // RNE
}

__device__ __forceinline__ us8 pack8(float4 a, float4 b) {
    us8 v;
    v[0] = f2bf(a.x); v[1] = f2bf(a.y); v[2] = f2bf(a.z); v[3] = f2bf(a.w);
    v[4] = f2bf(b.x); v[5] = f2bf(b.y); v[6] = f2bf(b.z); v[7] = f2bf(b.w);
    return v;
}

// 8 fp32 -> 8 bf16 via HW packed convert (RNE, bit-identical to f2bf; validated R2)
__device__ __forceinline__ bf8_t cvt8(float4 a, float4 b) {
    u32 r0, r1, r2, r3;
    asm("v_cvt_pk_bf16_f32 %0, %1, %2" : "=v"(r0) : "v"(a.x), "v"(a.y));
    asm("v_cvt_pk_bf16_f32 %0, %1, %2" : "=v"(r1) : "v"(a.z), "v"(a.w));
    asm("v_cvt_pk_bf16_f32 %0, %1, %2" : "=v"(r2) : "v"(b.x), "v"(b.y));
    asm("v_cvt_pk_bf16_f32 %0, %1, %2" : "=v"(r3) : "v"(b.z), "v"(b.w));
    union { u32 u[4]; bf8_t v; } cv;
    cv.u[0] = r0; cv.u[1] = r1; cv.u[2] = r2; cv.u[3] = r3;
    return cv.v;
}

// ---- kernel 1: fragment-major stacked B2: tiles 0..159 = Wn (10 ks x 16 nt),
// tiles 160..287 = Wa (8 ks x 16 nt). Tile = 64 lanes x 8 u16 (1KB). ----
__global__ __launch_bounds__(256) void build_b2(
    const float* __restrict__ Wn, const float* __restrict__ Wa,
    u16* __restrict__ B2)
{
    int tile = blockIdx.x * 4 + (threadIdx.x >> 6);   // 0..287
    int l = threadIdx.x & 63;
    int q = l >> 4, m = l & 15;
    us8 v;
    if (tile < 160) {
        int ks = tile >> 4, nt = tile & 15;
        int col = nt * 16 + m;
#pragma unroll
        for (int e = 0; e < 8; e++)
            v[e] = f2bf(Wn[(ks * 32 + q * 8 + e) * DNEW + col]);
    } else {
        int tt = tile - 160;
        int ks = tt >> 4, nt = tt & 15;
        int col = nt * 16 + m;
#pragma unroll
        for (int e = 0; e < 8; e++)
            v[e] = f2bf(Wa[(ks * 32 + q * 8 + e) * DNEW + col]);
    }
    *(us8*)&B2[(size_t)tile * 512 + l * 8] = v;
}

// ---- kernel 2: precompute h = atomf @ Wa + ba, fp32 to workspace.
// 16 atoms/block (512 blocks: 2/CU), staging loads batched for MLP. ----
__global__ __launch_bounds__(256) void h_pre(
    const float* __restrict__ atomf, const u16* __restrict__ B2,
    const float* __restrict__ ba, float* __restrict__ h_g)
{
    __shared__ u16 A[HATB * ASTR_H];   // 8448 B

    const int t = threadIdx.x;
    const int l = t & 63, w = t >> 6, q = l >> 4, m = l & 15;
    const int ab = blockIdx.x * HATB;

    // stage 16 atoms x 256 f32 -> bf16: 512 us8 chunks, 2/thread, loads batched
    const float* base = atomf + (size_t)ab * DNEW;
    float4 u0 = *(const float4*)(base + t * 8);
    float4 u1 = *(const float4*)(base + t * 8 + 4);
    float4 u2 = *(const float4*)(base + (t + 256) * 8);
    float4 u3 = *(const float4*)(base + (t + 256) * 8 + 4);
    int ai = t >> 5, c8 = t & 31;                 // (t+256)>>5 = ai+8, (t+256)&31 = c8
    *(us8*)&A[ai * ASTR_H + c8 * 8] = pack8(u0, u1);
    *(us8*)&A[(ai + 8) * ASTR_H + c8 * 8] = pack8(u2, u3);
    __syncthreads();

    f32x4 acc[4];
#pragma unroll
    for (int j = 0; j < 4; j++) acc[j] = (f32x4){0.f, 0.f, 0.f, 0.f};

#pragma unroll
    for (int ks = 0; ks < NKS_H; ks++) {
        bf8_t af = *(bf8_t*)&A[m * ASTR_H + ks * 32 + q * 8];
#pragma unroll
        for (int j = 0; j < 4; j++) {
            bf8_t bfj = *(const bf8_t*)&B2[((size_t)(160 + ks * 16 + w * 4 + j) * 64 + l) * 8];
            acc[j] = __builtin_amdgcn_mfma_f32_16x16x32_bf16(af, bfj, acc[j], 0, 0, 0);
        }
    }
#pragma unroll
    for (int j = 0; j < 4; j++) {
        int col = w * 64 + j * 16 + m;
        float bav = ba[col];
#pragma unroll
        for (int r = 0; r < 4; r++) {
            int row = ab + q * 4 + r;
            h_g[(size_t)row * DNEW + col] = acc[j][r] + bav;
        }
    }
}

// ---- kernel 3: fused e-GEMM + GATv2 attention + LN. 2 atoms/block.
// A staged via async global_load_lds DMA in FRAGMENT-MAJOR order (per-lane source
// swizzle): chunk c=(at*10+ks)*2+half is 1KB = 64 lanes x 16B granule. Lane (q,m)
// carries nbr row min(m,11), k-slice ks*32+q*8+half*4. Reads are 16B-stride
// ds_read_b128 (conflict-free). fp32->bf16 cvt in K-loop. red_l aliases dead A2. ----
__global__ __launch_bounds__(256, 4) void fused_all(
    const float* __restrict__ nbrf,
    const float* __restrict__ smaskg, const float* __restrict__ amaskg,
    const u16* __restrict__ B2, const float* __restrict__ h_g,
    const float* __restrict__ bnb, const float* __restrict__ walg,
    const float* __restrict__ balg, const float* __restrict__ gam,
    const float* __restrict__ bet, float* __restrict__ out)
{
    __shared__ __align__(16) float smem[NCHUNK * 256];   // 40960 B

    const int t = threadIdx.x;
    const int l = t & 63, w = t >> 6, q = l >> 4, m = l & 15;
    const int a0 = blockIdx.x * ATB;
    const bool qv = (q < 3);

    // ---- issue async A2 DMA first: 40 chunks, wave w takes c = w, w+4, ... ----
    const int srow = (m < KN) ? m : (KN - 1);   // clamp: pad lanes re-read row 11 (finite, masked later)
    for (int c = w; c < NCHUNK; c += 4) {
        int at = c / 20, rem = c - at * 20, ksc = rem >> 1, half = rem & 1;
        const float* src = nbrf + ((size_t)(a0 + at) * KN + srow) * DNBR
                         + ksc * 32 + q * 8 + half * 4;
        dma16(src, (char*)smem + (size_t)c * 1024);
    }

    // ---- params that feed the score phase (hide latency under DMA+GEMM) ----
    float hv[ATB][4], bnbv[4], wv[4];
#pragma unroll
    for (int j = 0; j < 4; j++) {
        int col = w * 64 + j * 16 + m;
        hv[0][j] = h_g[(size_t)(a0 + 0) * DNEW + col];
        hv[1][j] = h_g[(size_t)(a0 + 1) * DNEW + col];
        bnbv[j] = bnb[col];
        wv[j] = walg[(j * 16 + m) & 31];
    }

    __syncthreads();   // barrier 1: DMA drained (vmcnt(0) implicit), A2 ready

    // ---- e-GEMM: B2 loads issued first per ks, A via 16B-stride ds_read_b128 ----
    const float4* A2 = (const float4*)smem;
    f32x4 acc_e[ATB][4];
#pragma unroll
    for (int at = 0; at < ATB; at++)
#pragma unroll
        for (int j = 0; j < 4; j++) acc_e[at][j] = (f32x4){0.f, 0.f, 0.f, 0.f};

#pragma unroll
    for (int ks = 0; ks < NKS_E; ks++) {
        bf8_t bfj[4];
#pragma unroll
        for (int j = 0; j < 4; j++)
            bfj[j] = *(const bf8_t*)&B2[((size_t)(ks * 16 + w * 4 + j) * 64 + l) * 8];
        float4 lo0 = A2[(size_t)((0 * NKS_E + ks) * 2 + 0) * 64 + l];
        float4 hi0 = A2[(size_t)((0 * NKS_E + ks) * 2 + 1) * 64 + l];
        float4 lo1 = A2[(size_t)((1 * NKS_E + ks) * 2 + 0) * 64 + l];
        float4 hi1 = A2[(size_t)((1 * NKS_E + ks) * 2 + 1) * 64 + l];
        bf8_t af0 = cvt8(lo0, hi0);
        bf8_t af1 = cvt8(lo1, hi1);
#pragma unroll
        for (int j = 0; j < 4; j++) {
            acc_e[0][j] = __builtin_amdgcn_mfma_f32_16x16x32_bf16(af0, bfj[j], acc_e[0][j], 0, 0, 0);
            acc_e[1][j] = __builtin_amdgcn_mfma_f32_16x16x32_bf16(af1, bfj[j], acc_e[1][j], 0, 0, 0);
        }
    }

    // ---- mask params (loaded late to keep K-loop register pressure low) ----
    const float bal = balg[0];
    float smv[ATB][4], amv[ATB][4];
#pragma unroll
    for (int at = 0; at < ATB; at++)
#pragma unroll
        for (int r = 0; r < 4; r++) {
            int k = q * 4 + r;
            smv[at][r] = qv ? smaskg[(size_t)(a0 + at) * KN + k] + bal : 0.f;
            amv[at][r] = qv ? amaskg[(size_t)(a0 + at) * KN + k] : 0.f;
        }

    // ---- e_reg = acc_e + bnb (true e) ----
#pragma unroll
    for (int j = 0; j < 4; j++) {
#pragma unroll
        for (int at = 0; at < ATB; at++)
#pragma unroll
            for (int r = 0; r < 4; r++) acc_e[at][j][r] += bnbv[j];
    }

    // ---- scores + softmax + attn + ctx: all wave-local (wave w owns heads 2w,2w+1) ----
    float ctxv[ATB][4], s1s[ATB], s2s[ATB];
#pragma unroll
    for (int at = 0; at < ATB; at++) {
        float s1 = 0.f, s2 = 0.f;
#pragma unroll
        for (int jj = 0; jj < 2; jj++) {
            float p[4];
#pragma unroll
            for (int r = 0; r < 4; r++) {
                float pp = 0.f;
#pragma unroll
                for (int jo = 0; jo < 2; jo++) {
                    int j = jj * 2 + jo;
                    float f = acc_e[at][j][r] + hv[at][j];
                    f = f > 0.f ? f : 0.01f * f;
                    pp = fmaf(f, wv[j], pp);
                }
                pp += __shfl_xor(pp, 1);
                pp += __shfl_xor(pp, 2);
                pp += __shfl_xor(pp, 4);
                pp += __shfl_xor(pp, 8);
                p[r] = qv ? pp + smv[at][r] : -1e30f;
            }
            float mx = fmaxf(fmaxf(p[0], p[1]), fmaxf(p[2], p[3]));
            mx = fmaxf(mx, __shfl_xor(mx, 16));
            mx = fmaxf(mx, __shfl_xor(mx, 32));
            float ex[4], ss = 0.f;
#pragma unroll
            for (int r = 0; r < 4; r++) {
                ex[r] = qv ? __expf(p[r] - mx) : 0.f;
                ss += ex[r];
            }
            ss += __shfl_xor(ss, 16);
            ss += __shfl_xor(ss, 32);
            float inv = 1.f / ss;
            float am[4];
#pragma unroll
            for (int r = 0; r < 4; r++)
                am[r] = qv ? ex[r] * inv * amv[at][r] : 0.f;
#pragma unroll
            for (int jo = 0; jo < 2; jo++) {
                int j = jj * 2 + jo;
                float cp = am[0] * acc_e[at][j][0] + am[1] * acc_e[at][j][1] +
                           am[2] * acc_e[at][j][2] + am[3] * acc_e[at][j][3];
                cp += __shfl_xor(cp, 16);
                cp += __shfl_xor(cp, 32);
                ctxv[at][j] = cp;
                s1 += cp;
                s2 += cp * cp;
            }
        }
#pragma unroll
        for (int off = 1; off < 16; off <<= 1) {
            s1 += __shfl_xor(s1, off);
            s2 += __shfl_xor(s2, off);
        }
        s1s[at] = s1; s2s[at] = s2;
    }

    // ---- LN cross-wave reduce; red_l aliases A2 (dead after K-loop) ----
    float* red_l = smem;   // [ATB][8]
    __syncthreads();       // barrier 2: all waves done reading A2
    if (l == 0) {
#pragma unroll
        for (int at = 0; at < ATB; at++) {
            red_l[at * 8 + w] = s1s[at];
            red_l[at * 8 + 4 + w] = s2s[at];
        }
    }
    __syncthreads();       // barrier 3: red_l visible

    // ---- LayerNorm epilogue ----
#pragma unroll
    for (int at = 0; at < ATB; at++) {
        float ts1 = red_l[at * 8 + 0] + red_l[at * 8 + 1] + red_l[at * 8 + 2] + red_l[at * 8 + 3];
        float ts2 = red_l[at * 8 + 4] + red_l[at * 8 + 5] + red_l[at * 8 + 6] + red_l[at * 8 + 7];
        float mu = ts1 * (1.f / 256.f);
        float var = ts2 * (1.f / 256.f) - mu * mu;
        var = fmaxf(var, 0.f);
        float rs = rsqrtf(var + 1e-5f);
        if (q == 0) {
#pragma unroll
            for (int j = 0; j < 4; j++) {
                int col = w * 64 + j * 16 + m;
                out[(size_t)(a0 + at) * DNEW + col] =
                    (ctxv[at][j] - mu) * rs * gam[col] + bet[col];
            }
        }
    }
}

extern "C" void kernel_launch(void* const* d_in, const int* in_sizes, int n_in,
                              void* d_out, int out_size, void* d_ws, size_t ws_size,
                              hipStream_t stream) {
    const float* atomf = (const float*)d_in[0];
    const float* nbrf  = (const float*)d_in[1];
    const float* smask = (const float*)d_in[2];
    const float* amask = (const float*)d_in[3];
    const float* Wa    = (const float*)d_in[4];
    const float* ba    = (const float*)d_in[5];
    const float* Wn    = (const float*)d_in[6];
    const float* bnb   = (const float*)d_in[7];
    const float* wal   = (const float*)d_in[8];
    const float* bal   = (const float*)d_in[9];
    const float* gam   = (const float*)d_in[10];
    const float* bet   = (const float*)d_in[11];
    float* outp = (float*)d_out;

    u16* B2 = (u16*)d_ws;                              // 288 KiB
    float* h_g = (float*)((char*)d_ws + H_OFF);        // 8 MiB fp32 h

    build_b2<<<72, 256, 0, stream>>>(Wn, Wa, B2);
    h_pre<<<BN_TOT / HATB, 256, 0, stream>>>(atomf, B2, ba, h_g);
    fused_all<<<BN_TOT / ATB, 256, 0, stream>>>(nbrf, smask, amask, B2, h_g,
                                                bnb, wal, bal, gam, bet, outp);
}